// Round 8
// baseline (363.496 us; speedup 1.0000x reference)
//
#include <hip/hip_runtime.h>
#include <math.h>
#include <type_traits>

#define DIM 1024
#define NH 16
#define HD 64
#define BATCH 4
#define SEQ 2048
#define EPS 1e-6f

typedef __attribute__((ext_vector_type(8))) short short8;
typedef __attribute__((ext_vector_type(4))) short short4v;
typedef __attribute__((ext_vector_type(4))) float float4v;

// f32 -> bf16 round-to-nearest-even (scalar)
__device__ inline unsigned short f2bf(float f) {
    unsigned u = __float_as_uint(f);
    u += 0x7FFF + ((u >> 16) & 1);
    return (unsigned short)(u >> 16);
}
__device__ inline float bf2f(unsigned short b) {
    return __uint_as_float(((unsigned)b) << 16);
}
// pack two f32 -> two bf16 (round-half-up): 2 adds + 1 perm  [R6-proven]
__device__ inline unsigned pk2bf(float lo, float hi) {
    unsigned ul = __float_as_uint(lo) + 0x8000u;
    unsigned uh = __float_as_uint(hi) + 0x8000u;
    return __builtin_amdgcn_perm(uh, ul, 0x07060302u);
}

// [R6-proven exp2 path]
#if __has_builtin(__builtin_amdgcn_exp2f)
#define EXP2F(x) __builtin_amdgcn_exp2f(x)
#else
#define EXP2F(x) exp2f(x)
#endif

// 16x16x16 bf16 MFMA
#if __has_builtin(__builtin_amdgcn_mfma_f32_16x16x16bf16_1k)
__device__ inline float4v mfma16(short4v a, short4v b, float4v c) {
    return __builtin_amdgcn_mfma_f32_16x16x16bf16_1k(a, b, c, 0, 0, 0);
}
#elif __has_builtin(__builtin_amdgcn_mfma_f32_16x16x16_bf16)
__device__ inline float4v mfma16(short4v a, short4v b, float4v c) {
    return __builtin_amdgcn_mfma_f32_16x16x16_bf16(a, b, c, 0, 0, 0);
}
#else
__device__ inline float4v mfma16(short4v a, short4v b, float4v c) {
    asm volatile("v_mfma_f32_16x16x16_bf16 %0, %1, %2, %0\n\ts_nop 4"
                 : "+v"(c) : "v"(a), "v"(b));
    return c;
}
#endif

#define GLDS16(gp, lp) __builtin_amdgcn_global_load_lds( \
    (const __attribute__((address_space(1))) void*)(gp), \
    (__attribute__((address_space(3))) void*)(lp), 16, 0, 0)

// ---------------------------------------------------------------------------
// prep: x cast | qkv_w cast (q/k rows permuted for in-register RoPE) |
// proj_w cast | packed cos/sin table   [identical to R6]
// ---------------------------------------------------------------------------
__global__ __launch_bounds__(256) void prep_all(
    const float* __restrict__ x, const float* __restrict__ qkv_w,
    const float* __restrict__ proj_w,
    const float* __restrict__ cos_t, const float* __restrict__ sin_t,
    unsigned short* __restrict__ xb, unsigned short* __restrict__ qkvwb,
    unsigned short* __restrict__ projwb, unsigned* __restrict__ csP)
{
    const int bid = blockIdx.x;
    if (bid < 8192) {
        int i = bid * 256 + threadIdx.x;
        float4 f = ((const float4*)x)[i];
        ushort4 o;
        o.x = f2bf(f.x); o.y = f2bf(f.y); o.z = f2bf(f.z); o.w = f2bf(f.w);
        ((ushort4*)xb)[i] = o;
    } else if (bid < 8192 + 3072) {
        const int rn = bid - 8192;
        int ro = rn;
        if (rn < 2048) {
            const int head = rn >> 6, c = rn & 63, j = c >> 4, cl = c & 15;
            ro = (head << 6) + ((j & 1) + 2 * cl + 32 * (j >> 1));
        }
        float4 f = ((const float4*)(qkv_w + (long)ro * DIM))[threadIdx.x];
        ushort4 o;
        o.x = f2bf(f.x); o.y = f2bf(f.y); o.z = f2bf(f.z); o.w = f2bf(f.w);
        ((ushort4*)(qkvwb + (long)rn * DIM))[threadIdx.x] = o;
    } else if (bid < 8192 + 3072 + 1024) {
        int i = (bid - 11264) * 256 + threadIdx.x;
        float4 f = ((const float4*)proj_w)[i];
        ushort4 o;
        o.x = f2bf(f.x); o.y = f2bf(f.y); o.z = f2bf(f.z); o.w = f2bf(f.w);
        ((ushort4*)projwb)[i] = o;
    } else {
        int i = (bid - 12288) * 256 + threadIdx.x;
        int a = i >> 11, s = i & 2047;
        float c = cos_t[s * 64 + 2 * a], sn = sin_t[s * 64 + 2 * a];
        csP[a * SEQ + s] = ((unsigned)f2bf(sn) << 16) | f2bf(c);
    }
}

// ---------------------------------------------------------------------------
// Fused QKV GEMM + bias + RMSNorm + RoPE + V fragment store  [identical to R6]
// ---------------------------------------------------------------------------
__global__ __launch_bounds__(256) void gemm_qkv_fused(
    const unsigned short* __restrict__ A, const unsigned short* __restrict__ W,
    const float* __restrict__ bias, const unsigned* __restrict__ csP,
    const float* __restrict__ qw, const float* __restrict__ kw,
    unsigned short* __restrict__ q, unsigned short* __restrict__ k,
    unsigned short* __restrict__ vt)
{
    __shared__ __align__(16) unsigned short As[128 * 32];
    __shared__ __align__(16) unsigned short Bs[128 * 32];

    const int t    = threadIdx.x;
    const int lane = t & 63;
    const int w    = t >> 6;
    const int row0 = blockIdx.y * 128;
    const int col0 = blockIdx.x * 128;
    const int wr   = (w & 1) * 64;
    const int wc   = (w >> 1) * 64;
    const int cl   = lane & 15;
    const int quad = lane >> 4;

    float4v acc[4][4];
#pragma unroll
    for (int i = 0; i < 4; ++i)
#pragma unroll
        for (int j = 0; j < 4; ++j) acc[i][j] = (float4v){0.f, 0.f, 0.f, 0.f};

    const int off1 = t * 16, off2 = 4096 + t * 16;
    const int r1 = off1 >> 6, c1 = off1 & 63;
    const int r2 = off2 >> 6, c2 = off2 & 63;
    const char* Ab = (const char*)A + (long)row0 * DIM * 2;
    const char* Wb = (const char*)W + (long)col0 * DIM * 2;
    const long  ks = DIM * 2;

    for (int k0 = 0; k0 < DIM; k0 += 32) {
        const long kb = (long)k0 * 2;
        GLDS16(Ab + (long)r1 * ks + kb + c1, (char*)As + off1);
        GLDS16(Ab + (long)r2 * ks + kb + c2, (char*)As + off2);
        GLDS16(Wb + (long)r1 * ks + kb + c1, (char*)Bs + off1);
        GLDS16(Wb + (long)r2 * ks + kb + c2, (char*)Bs + off2);
        __syncthreads();

        short8 af[4], bfr[4];
#pragma unroll
        for (int i = 0; i < 4; ++i)
            af[i] = *(const short8*)&As[(wr + i * 16 + cl) * 32 + quad * 8];
#pragma unroll
        for (int j = 0; j < 4; ++j)
            bfr[j] = *(const short8*)&Bs[(wc + j * 16 + cl) * 32 + quad * 8];
#pragma unroll
        for (int i = 0; i < 4; ++i)
#pragma unroll
            for (int j = 0; j < 4; ++j)
                acc[i][j] = __builtin_amdgcn_mfma_f32_16x16x32_bf16(af[i], bfr[j], acc[i][j], 0, 0, 0);
        __syncthreads();
    }

    const int gcol  = col0 + wc;
    const int b     = row0 >> 11;
    const int srow0 = (row0 & 2047) + wr;

    if (gcol < 2 * DIM) {
        const bool isq = (gcol < DIM);
        const int  h   = (isq ? gcol : gcol - DIM) >> 6;
        const float* nw = isq ? qw : kw;
        const float scale = isq ? 0.180336880f : 1.0f;   // 0.125*log2(e)
        unsigned short* dst = (isq ? q : k) + (long)(b * NH + h) * SEQ * 64;

        float bjv[4];
#pragma unroll
        for (int j = 0; j < 4; ++j)
            bjv[j] = bias[gcol + (j & 1) + 2 * cl + 32 * (j >> 1)];
#pragma unroll
        for (int i = 0; i < 4; ++i)
#pragma unroll
            for (int j = 0; j < 4; ++j)
#pragma unroll
                for (int r = 0; r < 4; ++r) acc[i][j][r] += bjv[j];

        float rinv[4][4];
#pragma unroll
        for (int i = 0; i < 4; ++i)
#pragma unroll
            for (int r = 0; r < 4; ++r) {
                float ss = acc[i][0][r] * acc[i][0][r];
                ss = fmaf(acc[i][1][r], acc[i][1][r], ss);
                ss = fmaf(acc[i][2][r], acc[i][2][r], ss);
                ss = fmaf(acc[i][3][r], acc[i][3][r], ss);
                ss += __shfl_xor(ss, 1, 64);
                ss += __shfl_xor(ss, 2, 64);
                ss += __shfl_xor(ss, 4, 64);
                ss += __shfl_xor(ss, 8, 64);
                rinv[i][r] = rsqrtf(ss * (1.f / 64.f) + EPS) * scale;
            }

        const float nwe[2] = { nw[2 * cl],     nw[32 + 2 * cl] };
        const float nwo[2] = { nw[2 * cl + 1], nw[33 + 2 * cl] };

#pragma unroll
        for (int i = 0; i < 4; ++i) {
            const int sb = srow0 + i * 16 + quad * 4;
#pragma unroll
            for (int jp = 0; jp < 2; ++jp) {
                uint4 cs4 = *(const uint4*)(csP + (long)(jp * 16 + cl) * SEQ + sb);
#pragma unroll
                for (int r = 0; r < 4; ++r) {
                    float g  = rinv[i][r];
                    float xe = acc[i][2 * jp][r]     * g * nwe[jp];
                    float xo = acc[i][2 * jp + 1][r] * g * nwo[jp];
                    unsigned u = (r == 0) ? cs4.x : (r == 1) ? cs4.y : (r == 2) ? cs4.z : cs4.w;
                    float c  = bf2f((unsigned short)(u & 0xffff));
                    float sn = bf2f((unsigned short)(u >> 16));
                    float oe = fmaf(xe, c, -(xo * sn));
                    float oo = fmaf(xo, c,   xe * sn);
                    *(unsigned*)(dst + (long)(sb + r) * 64 + jp * 32 + 2 * cl) = pk2bf(oe, oo);
                }
            }
        }
    } else {
        const int h = (gcol - 2 * DIM) >> 6;
        float bjv[4];
#pragma unroll
        for (int j = 0; j < 4; ++j) bjv[j] = bias[gcol + j * 16 + cl];
        unsigned short* vdst = vt + (long)(b * NH + h) * SEQ * 64
                                  + (long)(srow0 >> 6) * 4096;
#pragma unroll
        for (int j = 0; j < 4; ++j)
#pragma unroll
            for (int ip = 0; ip < 2; ++ip) {
                const int i0 = 2 * ip;
                uint4 st;
                st.x = pk2bf(acc[i0][j][0] + bjv[j],     acc[i0][j][1] + bjv[j]);
                st.y = pk2bf(acc[i0][j][2] + bjv[j],     acc[i0][j][3] + bjv[j]);
                st.z = pk2bf(acc[i0 + 1][j][0] + bjv[j], acc[i0 + 1][j][1] + bjv[j]);
                st.w = pk2bf(acc[i0 + 1][j][2] + bjv[j], acc[i0 + 1][j][3] + bjv[j]);
                *(uint4*)(vdst + (j * 2 + ip) * 512 + lane * 8) = st;
            }
    }
}

// ---------------------------------------------------------------------------
// proj GEMM  [identical to R6]
// ---------------------------------------------------------------------------
__global__ __launch_bounds__(256) void gemm_proj(
    const unsigned short* __restrict__ A, const unsigned short* __restrict__ W,
    const float* __restrict__ bias, float* __restrict__ C)
{
    __shared__ __align__(16) unsigned short As[128 * 32];
    __shared__ __align__(16) unsigned short Bs[128 * 32];

    const int t    = threadIdx.x;
    const int lane = t & 63;
    const int w    = t >> 6;
    const int row0 = blockIdx.y * 128;
    const int col0 = blockIdx.x * 128;
    const int wr   = (w & 1) * 64;
    const int wc   = (w >> 1) * 64;

    float4v acc[4][4];
#pragma unroll
    for (int i = 0; i < 4; ++i)
#pragma unroll
        for (int j = 0; j < 4; ++j) acc[i][j] = (float4v){0.f, 0.f, 0.f, 0.f};

    const int off1 = t * 16, off2 = 4096 + t * 16;
    const int r1 = off1 >> 6, c1 = off1 & 63;
    const int r2 = off2 >> 6, c2 = off2 & 63;
    const char* Ab = (const char*)A + (long)row0 * DIM * 2;
    const char* Wb = (const char*)W + (long)col0 * DIM * 2;
    const long  ks = DIM * 2;

    for (int k0 = 0; k0 < DIM; k0 += 32) {
        const long kb = (long)k0 * 2;
        GLDS16(Ab + (long)r1 * ks + kb + c1, (char*)As + off1);
        GLDS16(Ab + (long)r2 * ks + kb + c2, (char*)As + off2);
        GLDS16(Wb + (long)r1 * ks + kb + c1, (char*)Bs + off1);
        GLDS16(Wb + (long)r2 * ks + kb + c2, (char*)Bs + off2);
        __syncthreads();

        short8 af[4], bfr[4];
#pragma unroll
        for (int i = 0; i < 4; ++i)
            af[i] = *(const short8*)&As[(wr + i * 16 + (lane & 15)) * 32 + (lane >> 4) * 8];
#pragma unroll
        for (int j = 0; j < 4; ++j)
            bfr[j] = *(const short8*)&Bs[(wc + j * 16 + (lane & 15)) * 32 + (lane >> 4) * 8];
#pragma unroll
        for (int i = 0; i < 4; ++i)
#pragma unroll
            for (int j = 0; j < 4; ++j)
                acc[i][j] = __builtin_amdgcn_mfma_f32_16x16x32_bf16(af[i], bfr[j], acc[i][j], 0, 0, 0);
        __syncthreads();
    }

    const int qd = lane >> 4, cl = lane & 15;
#pragma unroll
    for (int j = 0; j < 4; ++j) {
        const int col = col0 + wc + j * 16 + cl;
        const float bj = bias[col];
#pragma unroll
        for (int i = 0; i < 4; ++i) {
            const long rr = row0 + wr + i * 16 + qd * 4;
#pragma unroll
            for (int r = 0; r < 4; ++r)
                C[(rr + r) * (long)DIM + col] = acc[i][j][r] + bj;
        }
    }
}

// ---------------------------------------------------------------------------
// Flash attention: ZERO LDS, ZERO barriers. Q-tile 128 (2 q-groups/wave, all
// fragments in registers). K/V fragments read directly from global each iter
// (L1/L2 serve the redundancy). S^T form, exp2 softmax, row sums via
// ones-MFMA. Numerics identical to R6 (EXP2F + perm pk2bf).
// ---------------------------------------------------------------------------
__global__ __launch_bounds__(256) void flash_mfma(
    const unsigned short* __restrict__ q, const unsigned short* __restrict__ k,
    const unsigned short* __restrict__ vt, unsigned short* __restrict__ out)
{
    const int t    = threadIdx.x;
    const int lane = t & 63;
    const int w    = t >> 6;
    const int bh   = blockIdx.y;
    const int b    = bh >> 4;
    const int h    = bh & 15;
    const int q0   = blockIdx.x * 128;
    const int cl   = lane & 15;
    const int quad = lane >> 4;

    const char* qb  = (const char*)(q  + (long)bh * SEQ * 64);
    const char* kb  = (const char*)(k  + (long)bh * SEQ * 64);
    const char* vtb = (const char*)(vt + (long)bh * SEQ * 64);

    // Q fragments straight to registers (read once); wave w owns rows w*32..+32
    short8 aq[2][2];
#pragma unroll
    for (int qg = 0; qg < 2; ++qg)
#pragma unroll
        for (int hf = 0; hf < 2; ++hf)
            aq[qg][hf] = *(const short8*)(qb +
                (long)(q0 + w * 32 + qg * 16 + cl) * 128 + hf * 64 + quad * 16);

    const short4v ones = (short4v){(short)0x3F80, (short)0x3F80,
                                   (short)0x3F80, (short)0x3F80};

    float4v o[2][4], o4[2];
#pragma unroll
    for (int qg = 0; qg < 2; ++qg) {
        o4[qg] = (float4v){0.f, 0.f, 0.f, 0.f};
#pragma unroll
        for (int i = 0; i < 4; ++i) o[qg][i] = (float4v){0.f, 0.f, 0.f, 0.f};
    }

#pragma unroll 2
    for (int kt = 0; kt < SEQ / 64; ++kt) {
        // K fragments: 8 x b128 per wave
        const char* kbase = kb + (long)kt * 64 * 128;
        short8 kf[4][2];
#pragma unroll
        for (int j = 0; j < 4; ++j)
#pragma unroll
            for (int hf = 0; hf < 2; ++hf)
                kf[j][hf] = *(const short8*)(kbase +
                    (long)(j * 16 + cl) * 128 + hf * 64 + quad * 16);
        // V fragments (fragment-pair blob): 8 x b128, fully coalesced
        short8 vf[4][2];
#pragma unroll
        for (int fi = 0; fi < 4; ++fi)
#pragma unroll
            for (int jp = 0; jp < 2; ++jp)
                vf[fi][jp] = *(const short8*)(vtb + (long)kt * 8192 +
                    (fi * 2 + jp) * 1024 + lane * 16);

#pragma unroll
        for (int jp = 0; jp < 2; ++jp) {
            short4v pa[2][2];
#pragma unroll
            for (int qg = 0; qg < 2; ++qg) {
#pragma unroll
                for (int jj = 0; jj < 2; ++jj) {
                    const int j = jp * 2 + jj;
                    float4v z = (float4v){0.f, 0.f, 0.f, 0.f};
                    z = __builtin_amdgcn_mfma_f32_16x16x32_bf16(kf[j][0], aq[qg][0], z, 0, 0, 0);
                    z = __builtin_amdgcn_mfma_f32_16x16x32_bf16(kf[j][1], aq[qg][1], z, 0, 0, 0);
                    float p0 = EXP2F(z[0]), p1 = EXP2F(z[1]);
                    float p2 = EXP2F(z[2]), p3 = EXP2F(z[3]);
                    unsigned lo = pk2bf(p0, p1), hi = pk2bf(p2, p3);
                    pa[qg][jj] = __builtin_bit_cast(short4v,
                        ((unsigned long long)hi << 32) | lo);
                    o4[qg] = mfma16(ones, pa[qg][jj], o4[qg]);
                }
            }
#pragma unroll
            for (int fi = 0; fi < 4; ++fi) {
                short8 vv = vf[fi][jp];
                short4v va = __builtin_shufflevector(vv, vv, 0, 1, 2, 3);
                short4v vb = __builtin_shufflevector(vv, vv, 4, 5, 6, 7);
#pragma unroll
                for (int qg = 0; qg < 2; ++qg) {
                    o[qg][fi] = mfma16(va, pa[qg][0], o[qg][fi]);
                    o[qg][fi] = mfma16(vb, pa[qg][1], o[qg][fi]);
                }
            }
        }
    }

#pragma unroll
    for (int qg = 0; qg < 2; ++qg) {
        const float inv = 1.f / o4[qg][0];
        unsigned short* orow = out +
            ((long)b * SEQ + q0 + w * 32 + qg * 16 + cl) * DIM + h * 64;
#pragma unroll
        for (int i = 0; i < 4; ++i) {
            unsigned lo = pk2bf(o[qg][i][0] * inv, o[qg][i][1] * inv);
            unsigned hi = pk2bf(o[qg][i][2] * inv, o[qg][i][3] * inv);
            ushort4 st = __builtin_bit_cast(ushort4,
                ((unsigned long long)hi << 32) | lo);
            *(ushort4*)(orow + i * 16 + quad * 4) = st;
        }
    }
}

// ---------------------------------------------------------------------------
extern "C" void kernel_launch(void* const* d_in, const int* in_sizes, int n_in,
                              void* d_out, int out_size, void* d_ws, size_t ws_size,
                              hipStream_t stream)
{
    const float* x        = (const float*)d_in[0];
    const float* rope_cos = (const float*)d_in[1];
    const float* rope_sin = (const float*)d_in[2];
    const float* qkv_w    = (const float*)d_in[3];
    const float* qkv_b    = (const float*)d_in[4];
    const float* proj_w   = (const float*)d_in[5];
    const float* proj_b   = (const float*)d_in[6];
    const float* q_norm_w = (const float*)d_in[7];
    const float* k_norm_w = (const float*)d_in[8];
    float* outp = (float*)d_out;

    const int M = BATCH * SEQ;
    char* p = (char*)d_ws;
    unsigned short* xb    = (unsigned short*)p; p += (long)M * DIM * 2;
    unsigned short* qkvwb = (unsigned short*)p; p += (long)3 * DIM * DIM * 2;
    unsigned short* projwb= (unsigned short*)p; p += (long)DIM * DIM * 2;
    unsigned short* qb    = (unsigned short*)p; p += (long)M * DIM * 2;
    unsigned short* kbuf  = (unsigned short*)p; p += (long)M * DIM * 2;
    unsigned short* vtb   = (unsigned short*)p; p += (long)M * DIM * 2;
    unsigned short* attno = (unsigned short*)p; p += (long)M * DIM * 2;
    unsigned*       csP   = (unsigned*)p;       p += (long)32 * SEQ * 4;

    prep_all<<<dim3(12544), 256, 0, stream>>>(
        x, qkv_w, proj_w, rope_cos, rope_sin, xb, qkvwb, projwb, csP);

    gemm_qkv_fused<<<dim3(3 * DIM / 128, M / 128), 256, 0, stream>>>(
        xb, qkvwb, qkv_b, csP, q_norm_w, k_norm_w, qb, kbuf, vtb);

    flash_mfma<<<dim3(SEQ / 128, BATCH * NH), 256, 0, stream>>>(qb, kbuf, vtb, attno);

    gemm_proj<<<dim3(DIM / 128, M / 128), 256, 0, stream>>>(
        attno, projwb, proj_b, outp);
}

// Round 9
// 299.361 us; speedup vs baseline: 1.2142x; 1.2142x over previous
//
#include <hip/hip_runtime.h>
#include <math.h>
#include <type_traits>

#define DIM 1024
#define NH 16
#define HD 64
#define BATCH 4
#define SEQ 2048
#define EPS 1e-6f

typedef __attribute__((ext_vector_type(8))) short short8;
typedef __attribute__((ext_vector_type(4))) short short4v;
typedef __attribute__((ext_vector_type(4))) float float4v;

// f32 -> bf16 round-to-nearest-even (scalar)
__device__ inline unsigned short f2bf(float f) {
    unsigned u = __float_as_uint(f);
    u += 0x7FFF + ((u >> 16) & 1);
    return (unsigned short)(u >> 16);
}
__device__ inline float bf2f(unsigned short b) {
    return __uint_as_float(((unsigned)b) << 16);
}
// pack two f32 -> two bf16 (round-half-up): 2 adds + 1 perm  [proven]
__device__ inline unsigned pk2bf(float lo, float hi) {
    unsigned ul = __float_as_uint(lo) + 0x8000u;
    unsigned uh = __float_as_uint(hi) + 0x8000u;
    return __builtin_amdgcn_perm(uh, ul, 0x07060302u);
}

// [proven exp2 path]
#if __has_builtin(__builtin_amdgcn_exp2f)
#define EXP2F(x) __builtin_amdgcn_exp2f(x)
#else
#define EXP2F(x) exp2f(x)
#endif

// 16x16x16 bf16 MFMA
#if __has_builtin(__builtin_amdgcn_mfma_f32_16x16x16bf16_1k)
__device__ inline float4v mfma16(short4v a, short4v b, float4v c) {
    return __builtin_amdgcn_mfma_f32_16x16x16bf16_1k(a, b, c, 0, 0, 0);
}
#elif __has_builtin(__builtin_amdgcn_mfma_f32_16x16x16_bf16)
__device__ inline float4v mfma16(short4v a, short4v b, float4v c) {
    return __builtin_amdgcn_mfma_f32_16x16x16_bf16(a, b, c, 0, 0, 0);
}
#else
__device__ inline float4v mfma16(short4v a, short4v b, float4v c) {
    asm volatile("v_mfma_f32_16x16x16_bf16 %0, %1, %2, %0\n\ts_nop 4"
                 : "+v"(c) : "v"(a), "v"(b));
    return c;
}
#endif

#define GLDS16(gp, lp) __builtin_amdgcn_global_load_lds( \
    (const __attribute__((address_space(1))) void*)(gp), \
    (__attribute__((address_space(3))) void*)(lp), 16, 0, 0)

// ---------------------------------------------------------------------------
// prep: x cast | qkv_w cast (q/k rows permuted for in-register RoPE) |
// proj_w cast | packed cos/sin table   [identical to R6]
// ---------------------------------------------------------------------------
__global__ __launch_bounds__(256) void prep_all(
    const float* __restrict__ x, const float* __restrict__ qkv_w,
    const float* __restrict__ proj_w,
    const float* __restrict__ cos_t, const float* __restrict__ sin_t,
    unsigned short* __restrict__ xb, unsigned short* __restrict__ qkvwb,
    unsigned short* __restrict__ projwb, unsigned* __restrict__ csP)
{
    const int bid = blockIdx.x;
    if (bid < 8192) {
        int i = bid * 256 + threadIdx.x;
        float4 f = ((const float4*)x)[i];
        ushort4 o;
        o.x = f2bf(f.x); o.y = f2bf(f.y); o.z = f2bf(f.z); o.w = f2bf(f.w);
        ((ushort4*)xb)[i] = o;
    } else if (bid < 8192 + 3072) {
        const int rn = bid - 8192;
        int ro = rn;
        if (rn < 2048) {
            const int head = rn >> 6, c = rn & 63, j = c >> 4, cl = c & 15;
            ro = (head << 6) + ((j & 1) + 2 * cl + 32 * (j >> 1));
        }
        float4 f = ((const float4*)(qkv_w + (long)ro * DIM))[threadIdx.x];
        ushort4 o;
        o.x = f2bf(f.x); o.y = f2bf(f.y); o.z = f2bf(f.z); o.w = f2bf(f.w);
        ((ushort4*)(qkvwb + (long)rn * DIM))[threadIdx.x] = o;
    } else if (bid < 8192 + 3072 + 1024) {
        int i = (bid - 11264) * 256 + threadIdx.x;
        float4 f = ((const float4*)proj_w)[i];
        ushort4 o;
        o.x = f2bf(f.x); o.y = f2bf(f.y); o.z = f2bf(f.z); o.w = f2bf(f.w);
        ((ushort4*)projwb)[i] = o;
    } else {
        int i = (bid - 12288) * 256 + threadIdx.x;
        int a = i >> 11, s = i & 2047;
        float c = cos_t[s * 64 + 2 * a], sn = sin_t[s * 64 + 2 * a];
        csP[a * SEQ + s] = ((unsigned)f2bf(sn) << 16) | f2bf(c);
    }
}

// ---------------------------------------------------------------------------
// Fused QKV GEMM + bias + RMSNorm + RoPE + V fragment store  [identical to R6]
// ---------------------------------------------------------------------------
__global__ __launch_bounds__(256) void gemm_qkv_fused(
    const unsigned short* __restrict__ A, const unsigned short* __restrict__ W,
    const float* __restrict__ bias, const unsigned* __restrict__ csP,
    const float* __restrict__ qw, const float* __restrict__ kw,
    unsigned short* __restrict__ q, unsigned short* __restrict__ k,
    unsigned short* __restrict__ vt)
{
    __shared__ __align__(16) unsigned short As[128 * 32];
    __shared__ __align__(16) unsigned short Bs[128 * 32];

    const int t    = threadIdx.x;
    const int lane = t & 63;
    const int w    = t >> 6;
    const int row0 = blockIdx.y * 128;
    const int col0 = blockIdx.x * 128;
    const int wr   = (w & 1) * 64;
    const int wc   = (w >> 1) * 64;
    const int cl   = lane & 15;
    const int quad = lane >> 4;

    float4v acc[4][4];
#pragma unroll
    for (int i = 0; i < 4; ++i)
#pragma unroll
        for (int j = 0; j < 4; ++j) acc[i][j] = (float4v){0.f, 0.f, 0.f, 0.f};

    const int off1 = t * 16, off2 = 4096 + t * 16;
    const int r1 = off1 >> 6, c1 = off1 & 63;
    const int r2 = off2 >> 6, c2 = off2 & 63;
    const char* Ab = (const char*)A + (long)row0 * DIM * 2;
    const char* Wb = (const char*)W + (long)col0 * DIM * 2;
    const long  ks = DIM * 2;

    for (int k0 = 0; k0 < DIM; k0 += 32) {
        const long kb = (long)k0 * 2;
        GLDS16(Ab + (long)r1 * ks + kb + c1, (char*)As + off1);
        GLDS16(Ab + (long)r2 * ks + kb + c2, (char*)As + off2);
        GLDS16(Wb + (long)r1 * ks + kb + c1, (char*)Bs + off1);
        GLDS16(Wb + (long)r2 * ks + kb + c2, (char*)Bs + off2);
        __syncthreads();

        short8 af[4], bfr[4];
#pragma unroll
        for (int i = 0; i < 4; ++i)
            af[i] = *(const short8*)&As[(wr + i * 16 + cl) * 32 + quad * 8];
#pragma unroll
        for (int j = 0; j < 4; ++j)
            bfr[j] = *(const short8*)&Bs[(wc + j * 16 + cl) * 32 + quad * 8];
#pragma unroll
        for (int i = 0; i < 4; ++i)
#pragma unroll
            for (int j = 0; j < 4; ++j)
                acc[i][j] = __builtin_amdgcn_mfma_f32_16x16x32_bf16(af[i], bfr[j], acc[i][j], 0, 0, 0);
        __syncthreads();
    }

    const int gcol  = col0 + wc;
    const int b     = row0 >> 11;
    const int srow0 = (row0 & 2047) + wr;

    if (gcol < 2 * DIM) {
        const bool isq = (gcol < DIM);
        const int  h   = (isq ? gcol : gcol - DIM) >> 6;
        const float* nw = isq ? qw : kw;
        const float scale = isq ? 0.180336880f : 1.0f;   // 0.125*log2(e)
        unsigned short* dst = (isq ? q : k) + (long)(b * NH + h) * SEQ * 64;

        float bjv[4];
#pragma unroll
        for (int j = 0; j < 4; ++j)
            bjv[j] = bias[gcol + (j & 1) + 2 * cl + 32 * (j >> 1)];
#pragma unroll
        for (int i = 0; i < 4; ++i)
#pragma unroll
            for (int j = 0; j < 4; ++j)
#pragma unroll
                for (int r = 0; r < 4; ++r) acc[i][j][r] += bjv[j];

        float rinv[4][4];
#pragma unroll
        for (int i = 0; i < 4; ++i)
#pragma unroll
            for (int r = 0; r < 4; ++r) {
                float ss = acc[i][0][r] * acc[i][0][r];
                ss = fmaf(acc[i][1][r], acc[i][1][r], ss);
                ss = fmaf(acc[i][2][r], acc[i][2][r], ss);
                ss = fmaf(acc[i][3][r], acc[i][3][r], ss);
                ss += __shfl_xor(ss, 1, 64);
                ss += __shfl_xor(ss, 2, 64);
                ss += __shfl_xor(ss, 4, 64);
                ss += __shfl_xor(ss, 8, 64);
                rinv[i][r] = rsqrtf(ss * (1.f / 64.f) + EPS) * scale;
            }

        const float nwe[2] = { nw[2 * cl],     nw[32 + 2 * cl] };
        const float nwo[2] = { nw[2 * cl + 1], nw[33 + 2 * cl] };

#pragma unroll
        for (int i = 0; i < 4; ++i) {
            const int sb = srow0 + i * 16 + quad * 4;
#pragma unroll
            for (int jp = 0; jp < 2; ++jp) {
                uint4 cs4 = *(const uint4*)(csP + (long)(jp * 16 + cl) * SEQ + sb);
#pragma unroll
                for (int r = 0; r < 4; ++r) {
                    float g  = rinv[i][r];
                    float xe = acc[i][2 * jp][r]     * g * nwe[jp];
                    float xo = acc[i][2 * jp + 1][r] * g * nwo[jp];
                    unsigned u = (r == 0) ? cs4.x : (r == 1) ? cs4.y : (r == 2) ? cs4.z : cs4.w;
                    float c  = bf2f((unsigned short)(u & 0xffff));
                    float sn = bf2f((unsigned short)(u >> 16));
                    float oe = fmaf(xe, c, -(xo * sn));
                    float oo = fmaf(xo, c,   xe * sn);
                    *(unsigned*)(dst + (long)(sb + r) * 64 + jp * 32 + 2 * cl) = pk2bf(oe, oo);
                }
            }
        }
    } else {
        const int h = (gcol - 2 * DIM) >> 6;
        float bjv[4];
#pragma unroll
        for (int j = 0; j < 4; ++j) bjv[j] = bias[gcol + j * 16 + cl];
        unsigned short* vdst = vt + (long)(b * NH + h) * SEQ * 64
                                  + (long)(srow0 >> 6) * 4096;
#pragma unroll
        for (int j = 0; j < 4; ++j)
#pragma unroll
            for (int ip = 0; ip < 2; ++ip) {
                const int i0 = 2 * ip;
                uint4 st;
                st.x = pk2bf(acc[i0][j][0] + bjv[j],     acc[i0][j][1] + bjv[j]);
                st.y = pk2bf(acc[i0][j][2] + bjv[j],     acc[i0][j][3] + bjv[j]);
                st.z = pk2bf(acc[i0 + 1][j][0] + bjv[j], acc[i0 + 1][j][1] + bjv[j]);
                st.w = pk2bf(acc[i0 + 1][j][2] + bjv[j], acc[i0 + 1][j][3] + bjv[j]);
                *(uint4*)(vdst + (j * 2 + ip) * 512 + lane * 8) = st;
            }
    }
}

// ---------------------------------------------------------------------------
// proj GEMM  [identical to R6]
// ---------------------------------------------------------------------------
__global__ __launch_bounds__(256) void gemm_proj(
    const unsigned short* __restrict__ A, const unsigned short* __restrict__ W,
    const float* __restrict__ bias, float* __restrict__ C)
{
    __shared__ __align__(16) unsigned short As[128 * 32];
    __shared__ __align__(16) unsigned short Bs[128 * 32];

    const int t    = threadIdx.x;
    const int lane = t & 63;
    const int w    = t >> 6;
    const int row0 = blockIdx.y * 128;
    const int col0 = blockIdx.x * 128;
    const int wr   = (w & 1) * 64;
    const int wc   = (w >> 1) * 64;

    float4v acc[4][4];
#pragma unroll
    for (int i = 0; i < 4; ++i)
#pragma unroll
        for (int j = 0; j < 4; ++j) acc[i][j] = (float4v){0.f, 0.f, 0.f, 0.f};

    const int off1 = t * 16, off2 = 4096 + t * 16;
    const int r1 = off1 >> 6, c1 = off1 & 63;
    const int r2 = off2 >> 6, c2 = off2 & 63;
    const char* Ab = (const char*)A + (long)row0 * DIM * 2;
    const char* Wb = (const char*)W + (long)col0 * DIM * 2;
    const long  ks = DIM * 2;

    for (int k0 = 0; k0 < DIM; k0 += 32) {
        const long kb = (long)k0 * 2;
        GLDS16(Ab + (long)r1 * ks + kb + c1, (char*)As + off1);
        GLDS16(Ab + (long)r2 * ks + kb + c2, (char*)As + off2);
        GLDS16(Wb + (long)r1 * ks + kb + c1, (char*)Bs + off1);
        GLDS16(Wb + (long)r2 * ks + kb + c2, (char*)Bs + off2);
        __syncthreads();

        short8 af[4], bfr[4];
#pragma unroll
        for (int i = 0; i < 4; ++i)
            af[i] = *(const short8*)&As[(wr + i * 16 + (lane & 15)) * 32 + (lane >> 4) * 8];
#pragma unroll
        for (int j = 0; j < 4; ++j)
            bfr[j] = *(const short8*)&Bs[(wc + j * 16 + (lane & 15)) * 32 + (lane >> 4) * 8];
#pragma unroll
        for (int i = 0; i < 4; ++i)
#pragma unroll
            for (int j = 0; j < 4; ++j)
                acc[i][j] = __builtin_amdgcn_mfma_f32_16x16x32_bf16(af[i], bfr[j], acc[i][j], 0, 0, 0);
        __syncthreads();
    }

    const int qd = lane >> 4, cl = lane & 15;
#pragma unroll
    for (int j = 0; j < 4; ++j) {
        const int col = col0 + wc + j * 16 + cl;
        const float bj = bias[col];
#pragma unroll
        for (int i = 0; i < 4; ++i) {
            const long rr = row0 + wr + i * 16 + qd * 4;
#pragma unroll
            for (int r = 0; r < 4; ++r)
                C[(rr + r) * (long)DIM + col] = acc[i][j][r] + bj;
        }
    }
}

// ---------------------------------------------------------------------------
// MFMA flash attention [R6 structure]. Q-tile 128, 2 q-groups/wave. ONE change
// vs R6: Q fragments load straight from global into registers (outside the
// K-loop) -- no Qs LDS. LDS = K(8KB)+V(8KB) = 16 KB, doubling the LDS
// block-residency cap for cross-block staging/compute overlap.
// ---------------------------------------------------------------------------
__global__ __launch_bounds__(256) void flash_mfma(
    const unsigned short* __restrict__ q, const unsigned short* __restrict__ k,
    const unsigned short* __restrict__ vt, unsigned short* __restrict__ out)
{
    __shared__ __align__(16) unsigned short Ks[2][64 * 32];
    __shared__ __align__(16) unsigned short Vts[64 * 64];

    const int t    = threadIdx.x;
    const int lane = t & 63;
    const int w    = t >> 6;
    const int bh   = blockIdx.y;
    const int b    = bh >> 4;
    const int h    = bh & 15;
    const int q0   = blockIdx.x * 128;
    const int cl   = lane & 15;
    const int quad = lane >> 4;

    const char* qb  = (const char*)(q  + (long)bh * SEQ * 64);
    const char* kb  = (const char*)(k  + (long)bh * SEQ * 64);
    const char* vtb = (const char*)(vt + (long)bh * SEQ * 64);

    // Q fragments straight to registers (read once, outside the loop)
    short8 aq[2][2];
#pragma unroll
    for (int qg = 0; qg < 2; ++qg)
#pragma unroll
        for (int hf = 0; hf < 2; ++hf)
            aq[qg][hf] = *(const short8*)(qb +
                (long)(q0 + w * 32 + qg * 16 + cl) * 128 + hf * 64 + quad * 16);

    const short4v ones = (short4v){(short)0x3F80, (short)0x3F80,
                                   (short)0x3F80, (short)0x3F80};

    float4v o[2][4], o4[2];
#pragma unroll
    for (int qg = 0; qg < 2; ++qg) {
        o4[qg] = (float4v){0.f, 0.f, 0.f, 0.f};
#pragma unroll
        for (int i = 0; i < 4; ++i) o[qg][i] = (float4v){0.f, 0.f, 0.f, 0.f};
    }

    const int soff = t * 16, srow = soff >> 6, scb = soff & 63;

    for (int kt = 0; kt < SEQ / 64; ++kt) {
#pragma unroll
        for (int hf = 0; hf < 2; ++hf)
            GLDS16(kb + (long)(kt * 64 + srow) * 128 + hf * 64 + scb, (char*)Ks[hf] + soff);
        GLDS16(vtb + (long)kt * 8192 + t * 16,        (char*)Vts + t * 16);
        GLDS16(vtb + (long)kt * 8192 + 4096 + t * 16, (char*)Vts + 4096 + t * 16);
        __syncthreads();

        short4v pa[2][4];
#pragma unroll
        for (int j = 0; j < 4; ++j) {
            short8 a0 = *(const short8*)&Ks[0][(j * 16 + cl) * 32 + quad * 8];
            short8 a1 = *(const short8*)&Ks[1][(j * 16 + cl) * 32 + quad * 8];
#pragma unroll
            for (int qg = 0; qg < 2; ++qg) {
                float4v z = (float4v){0.f, 0.f, 0.f, 0.f};
                z = __builtin_amdgcn_mfma_f32_16x16x32_bf16(a0, aq[qg][0], z, 0, 0, 0);
                float4v s = __builtin_amdgcn_mfma_f32_16x16x32_bf16(a1, aq[qg][1], z, 0, 0, 0);
                float p0 = EXP2F(s[0]), p1 = EXP2F(s[1]);
                float p2 = EXP2F(s[2]), p3 = EXP2F(s[3]);
                unsigned lo = pk2bf(p0, p1), hi = pk2bf(p2, p3);
                pa[qg][j] = __builtin_bit_cast(short4v, ((unsigned long long)hi << 32) | lo);
                o4[qg] = mfma16(ones, pa[qg][j], o4[qg]);   // row sums on MFMA pipe
            }
        }

        // O^T += V^T @ P^T (V fragments shared across both q-groups)
#pragma unroll
        for (int fi = 0; fi < 4; ++fi) {
#pragma unroll
            for (int fjp = 0; fjp < 2; ++fjp) {
                short8 vv = *(const short8*)&Vts[(fi * 2 + fjp) * 512 + lane * 8];
                short4v va = __builtin_shufflevector(vv, vv, 0, 1, 2, 3);
                short4v vb = __builtin_shufflevector(vv, vv, 4, 5, 6, 7);
#pragma unroll
                for (int qg = 0; qg < 2; ++qg) {
                    o[qg][fi] = mfma16(va, pa[qg][2 * fjp],     o[qg][fi]);
                    o[qg][fi] = mfma16(vb, pa[qg][2 * fjp + 1], o[qg][fi]);
                }
            }
        }
        __syncthreads();
    }

#pragma unroll
    for (int qg = 0; qg < 2; ++qg) {
        const float inv = 1.f / o4[qg][0];
        unsigned short* orow = out + ((long)b * SEQ + q0 + w * 32 + qg * 16 + cl) * DIM + h * 64;
#pragma unroll
        for (int i = 0; i < 4; ++i) {
            unsigned lo = pk2bf(o[qg][i][0] * inv, o[qg][i][1] * inv);
            unsigned hi = pk2bf(o[qg][i][2] * inv, o[qg][i][3] * inv);
            ushort4 st = __builtin_bit_cast(ushort4, ((unsigned long long)hi << 32) | lo);
            *(ushort4*)(orow + i * 16 + quad * 4) = st;
        }
    }
}

// ---------------------------------------------------------------------------
extern "C" void kernel_launch(void* const* d_in, const int* in_sizes, int n_in,
                              void* d_out, int out_size, void* d_ws, size_t ws_size,
                              hipStream_t stream)
{
    const float* x        = (const float*)d_in[0];
    const float* rope_cos = (const float*)d_in[1];
    const float* rope_sin = (const float*)d_in[2];
    const float* qkv_w    = (const float*)d_in[3];
    const float* qkv_b    = (const float*)d_in[4];
    const float* proj_w   = (const float*)d_in[5];
    const float* proj_b   = (const float*)d_in[6];
    const float* q_norm_w = (const float*)d_in[7];
    const float* k_norm_w = (const float*)d_in[8];
    float* outp = (float*)d_out;

    const int M = BATCH * SEQ;
    char* p = (char*)d_ws;
    unsigned short* xb    = (unsigned short*)p; p += (long)M * DIM * 2;
    unsigned short* qkvwb = (unsigned short*)p; p += (long)3 * DIM * DIM * 2;
    unsigned short* projwb= (unsigned short*)p; p += (long)DIM * DIM * 2;
    unsigned short* qb    = (unsigned short*)p; p += (long)M * DIM * 2;
    unsigned short* kbuf  = (unsigned short*)p; p += (long)M * DIM * 2;
    unsigned short* vtb   = (unsigned short*)p; p += (long)M * DIM * 2;
    unsigned short* attno = (unsigned short*)p; p += (long)M * DIM * 2;
    unsigned*       csP   = (unsigned*)p;       p += (long)32 * SEQ * 4;

    prep_all<<<dim3(12544), 256, 0, stream>>>(
        x, qkv_w, proj_w, rope_cos, rope_sin, xb, qkvwb, projwb, csP);

    gemm_qkv_fused<<<dim3(3 * DIM / 128, M / 128), 256, 0, stream>>>(
        xb, qkvwb, qkv_b, csP, q_norm_w, k_norm_w, qb, kbuf, vtb);

    flash_mfma<<<dim3(SEQ / 128, BATCH * NH), 256, 0, stream>>>(qb, kbuf, vtb, attno);

    gemm_proj<<<dim3(DIM / 128, M / 128), 256, 0, stream>>>(
        attno, projwb, proj_b, outp);
}